// Round 10
// baseline (71.693 us; speedup 1.0000x reference)
//
#include <hip/hip_runtime.h>
#include <math.h>

#define NTH 256

static constexpr float HLP = 0.9189385332046727f; // 0.5*log(2*pi)

typedef __attribute__((ext_vector_type(2))) _Float16 half2v;
typedef __attribute__((ext_vector_type(2))) __fp16   fp16x2;

// ===================== main-path ws layout =====================
// [0, 524288)        L3 n f16-packed uint4 [16][8192]  (uint4 idx r3*8192+b)
// [524288, 655360)   L3 M f32 [16][8192]
static constexpr int L3MF = 524288;
static constexpr size_t WS_NEED_B = (size_t)655360 * 4;   // 2.62 MB

// ===================== helpers =====================
__device__ __forceinline__ half2v pkrtz(float a, float b) {
  return __builtin_bit_cast(half2v, __builtin_amdgcn_cvt_pkrtz(a, b));
}
__device__ __forceinline__ half2v u2h(unsigned u) {
  return __builtin_bit_cast(half2v, u);
}
__device__ __forceinline__ unsigned h2u(half2v h) {
  return __builtin_bit_cast(unsigned, h);
}
__device__ __forceinline__ float dd(half2v a, half2v b, float c) {
#if __has_builtin(__builtin_amdgcn_fdot2)
  return __builtin_amdgcn_fdot2(__builtin_bit_cast(fp16x2, a),
                                __builtin_bit_cast(fp16x2, b), c, false);
#else
  return fmaf((float)a[0], (float)b[0], fmaf((float)a[1], (float)b[1], c));
#endif
}
__device__ __forceinline__ float max8(const float* s) {
  float m = s[0];
  #pragma unroll
  for (int k = 1; k < 8; ++k) m = fmaxf(m, s[k]);
  return m;
}

__device__ __forceinline__ void leaf_ii(float xv, const float* mu8, const float* A8,
                                        const float* B8, half2v* ii, float* M) {
  float h[8];
  float m = -3.0e38f;
  #pragma unroll
  for (int k = 0; k < 8; ++k) {
    const float z = (xv - mu8[k]) * A8[k];
    h[k] = fmaf(-0.5f * z, z, B8[k]);
    m = fmaxf(m, h[k]);
  }
  #pragma unroll
  for (int k = 0; k < 8; ++k) {
    const float n = __expf(h[k] - m);
    ii[k] = pkrtz(n, n);
  }
  *M = m;
}
__device__ __forceinline__ void leaf_pk(float xv, const float* mu8, const float* A8,
                                        const float* B8, half2v* pk, float* M) {
  float h[8];
  float m = -3.0e38f;
  #pragma unroll
  for (int k = 0; k < 8; ++k) {
    const float z = (xv - mu8[k]) * A8[k];
    h[k] = fmaf(-0.5f * z, z, B8[k]);
    m = fmaxf(m, h[k]);
  }
  #pragma unroll
  for (int p = 0; p < 4; ++p) {
    const float n0 = __expf(h[2 * p] - m);
    const float n1 = __expf(h[2 * p + 1] - m);
    pk[p] = pkrtz(n0, n1);
  }
  *M = m;
}

// combine via dot2: s[k] = sum_{i,j} na_i nb_j W[i*8+j][k]
template<int G, bool OUT_II>
__device__ __forceinline__ void combine_d2(const uint4* __restrict__ WL,
                                           const half2v (&na)[G][8],
                                           const half2v (&nb)[G][4],
                                           half2v (&oii)[G][8],
                                           half2v (&opk)[G][4],
                                           float (&M)[G]) {
  float s[G][8];
  #pragma unroll
  for (int g = 0; g < G; ++g)
    #pragma unroll
    for (int k = 0; k < 8; ++k) s[g][k] = 0.f;

  #pragma unroll
  for (int i = 0; i < 8; ++i) {
    half2v e[G][4];
    #pragma unroll
    for (int g = 0; g < G; ++g) {
      e[g][0] = na[g][i] * nb[g][0];
      e[g][1] = na[g][i] * nb[g][1];
      e[g][2] = na[g][i] * nb[g][2];
      e[g][3] = na[g][i] * nb[g][3];
    }
    #pragma unroll
    for (int k = 0; k < 8; ++k) {
      const uint4 w = WL[i * 8 + k];
      #pragma unroll
      for (int g = 0; g < G; ++g) {
        float acc = s[g][k];
        acc = dd(e[g][0], u2h(w.x), acc);
        acc = dd(e[g][1], u2h(w.y), acc);
        acc = dd(e[g][2], u2h(w.z), acc);
        acc = dd(e[g][3], u2h(w.w), acc);
        s[g][k] = acc;
      }
    }
  }
  #pragma unroll
  for (int g = 0; g < G; ++g) {
    const float smax = max8(s[g]);
    const float inv = 1.0f / smax;
    if constexpr (OUT_II) {
      #pragma unroll
      for (int p = 0; p < 8; ++p) {
        const float n = s[g][p] * inv;
        oii[g][p] = pkrtz(n, n);
      }
    } else {
      #pragma unroll
      for (int p = 0; p < 4; ++p)
        opk[g][p] = pkrtz(s[g][2 * p] * inv, s[g][2 * p + 1] * inv);
    }
    M[g] += __logf(smax);
  }
}

// block-local softmax of one column (r,k) from stage into packed [c][k]-pair layout
__device__ __forceinline__ void prep_col_std(const float* stage, unsigned* wdwL,
                                             int r, int k) {
  float v[64];
  float m = -3.0e38f;
  #pragma unroll
  for (int c = 0; c < 64; ++c) { v[c] = stage[r * 512 + c * 8 + k]; m = fmaxf(m, v[c]); }
  float t = 0.f;
  #pragma unroll
  for (int c = 0; c < 64; ++c) { v[c] = __expf(v[c] - m); t += v[c]; }
  const float inv = 1.0f / t;
  #pragma unroll
  for (int i = 0; i < 8; ++i)
    #pragma unroll
    for (int jp = 0; jp < 4; ++jp)
      wdwL[r * 256 + (i * 8 + k) * 4 + jp] =
          h2u(pkrtz(v[i * 8 + 2 * jp] * inv, v[i * 8 + 2 * jp + 1] * inv));
}

// one subtree (2x L0 + L1) for G=2 batches; xa/xb = 4 features' x for each batch
template<bool OUT_II>
__device__ __forceinline__ void subtree2(const uint4* __restrict__ wsh4, int sub,
                                         const float* lsh, float4 xa, float4 xb,
                                         half2v (&oii)[2][8], half2v (&opk)[2][4],
                                         float (&Mout)[2]) {
  half2v ii[2][8], pk[2][4];
  half2v aii[2][8], bpk[2][4];
  half2v dii[2][8], dpk[2][4];
  float Ma, Mb;
  const int fl = 4 * sub;
  const float* m0 = lsh + fl * 8;
  const float* A0 = lsh + 128 + fl * 8;
  const float* B0 = lsh + 256 + fl * 8;

  leaf_ii(xa.x, m0,      A0,      B0,      ii[0], &Ma);
  leaf_pk(xa.y, m0 + 8,  A0 + 8,  B0 + 8,  pk[0], &Mb);
  float MA[2];
  MA[0] = Ma + Mb;
  leaf_ii(xb.x, m0,      A0,      B0,      ii[1], &Ma);
  leaf_pk(xb.y, m0 + 8,  A0 + 8,  B0 + 8,  pk[1], &Mb);
  MA[1] = Ma + Mb;
  combine_d2<2, true>(wsh4 + (2 * sub) * 64, ii, pk, aii, dpk, MA);

  leaf_ii(xa.z, m0 + 16, A0 + 16, B0 + 16, ii[0], &Ma);
  leaf_pk(xa.w, m0 + 24, A0 + 24, B0 + 24, pk[0], &Mb);
  float MB[2];
  MB[0] = Ma + Mb;
  leaf_ii(xb.z, m0 + 16, A0 + 16, B0 + 16, ii[1], &Ma);
  leaf_pk(xb.w, m0 + 24, A0 + 24, B0 + 24, pk[1], &Mb);
  MB[1] = Ma + Mb;
  combine_d2<2, false>(wsh4 + (2 * sub + 1) * 64, ii, pk, dii, bpk, MB);

  float M[2] = {MA[0] + MB[0], MA[1] + MB[1]};
  combine_d2<2, OUT_II>(wsh4 + (8 + sub) * 64, aii, bpk, oii, opk, M);
  Mout[0] = M[0];
  Mout[1] = M[1];
}

// ===================== K1: fused L0..L3, G=2 batches/thread =====================
// grid: 16 r3 x 32 chunks = 512 blocks x 128 thr; thread = 2 batches (b0, b0+128)
__global__ __launch_bounds__(128, 2) void spn_ab2(
    const float* __restrict__ x,
    const float* __restrict__ mu,
    const float* __restrict__ ls,
    const float* __restrict__ w0, const float* __restrict__ w1,
    const float* __restrict__ w2, const float* __restrict__ w3,
    float* __restrict__ ws)
{
  __shared__ float stage[7680];   // 15 regions x 512 f32 = 30 KB
  __shared__ uint4 wsh4[960];     // 15 regions x 64 uint4 = 15 KB packed f16
  __shared__ float lsh[384];      // mu/A/B for 16 features x 8
  const int tid = threadIdx.x;
  const int r3 = blockIdx.x >> 5;
  const int chunk = blockIdx.x & 31;

  // stage raw weights for this block's 15 regions (coalesced)
  #pragma unroll
  for (int i = 0; i < 60; ++i) {
    const int idx = tid + 128 * i;
    const int reg = idx >> 9, off = idx & 511;
    const float* src;
    if (reg < 8)       src = w0 + (8 * r3 + reg) * 512;
    else if (reg < 12) src = w1 + (4 * r3 + (reg - 8)) * 512;
    else if (reg < 14) src = w2 + (2 * r3 + (reg - 12)) * 512;
    else               src = w3 + r3 * 512;
    stage[idx] = src[off];
  }
  {
    const int base = r3 * 128;   // 16 features x 8
    const float l = ls[base + tid];
    lsh[tid]       = mu[base + tid];
    lsh[128 + tid] = __expf(-l);
    lsh[256 + tid] = -l - HLP;
  }
  __syncthreads();

  if (tid < 120) prep_col_std(stage, reinterpret_cast<unsigned*>(wsh4), tid >> 3, tid & 7);
  __syncthreads();

  const int b0 = chunk * 256 + tid;          // batches b0, b0+128
  const float* xa = x + (size_t)b0 * 256 + 16 * r3;
  const float* xb = x + (size_t)(b0 + 128) * 256 + 16 * r3;
  const float4 xa0 = *reinterpret_cast<const float4*>(xa);
  const float4 xa1 = *reinterpret_cast<const float4*>(xa + 4);
  const float4 xa2 = *reinterpret_cast<const float4*>(xa + 8);
  const float4 xa3 = *reinterpret_cast<const float4*>(xa + 12);
  const float4 xb0 = *reinterpret_cast<const float4*>(xb);
  const float4 xb1 = *reinterpret_cast<const float4*>(xb + 4);
  const float4 xb2 = *reinterpret_cast<const float4*>(xb + 8);
  const float4 xb3 = *reinterpret_cast<const float4*>(xb + 12);

  half2v s0ii[2][8], s1pk[2][4], s2ii[2][8], s3pk[2][4];
  half2v dii[2][8], dpk[2][4];
  float M0[2], M1[2], M2[2], M3[2];

  subtree2<true >(wsh4, 0, lsh, xa0, xb0, s0ii, dpk, M0);
  subtree2<false>(wsh4, 1, lsh, xa1, xb1, dii, s1pk, M1);
  float MA[2] = {M0[0] + M1[0], M0[1] + M1[1]};
  half2v cAii[2][8];
  combine_d2<2, true>(wsh4 + 12 * 64, s0ii, s1pk, cAii, dpk, MA);

  subtree2<true >(wsh4, 2, lsh, xa2, xb2, s2ii, dpk, M2);
  subtree2<false>(wsh4, 3, lsh, xa3, xb3, dii, s3pk, M3);
  float MB[2] = {M2[0] + M3[0], M2[1] + M3[1]};
  half2v cBpk[2][4];
  combine_d2<2, false>(wsh4 + 13 * 64, s2ii, s3pk, dii, cBpk, MB);

  float M[2] = {MA[0] + MB[0], MA[1] + MB[1]};
  half2v n[2][4];
  combine_d2<2, false>(wsh4 + 14 * 64, cAii, cBpk, dii, n, M);

  uint4* outn = reinterpret_cast<uint4*>(ws);
  outn[r3 * 8192 + b0] =
      uint4{h2u(n[0][0]), h2u(n[0][1]), h2u(n[0][2]), h2u(n[0][3])};
  outn[r3 * 8192 + b0 + 128] =
      uint4{h2u(n[1][0]), h2u(n[1][1]), h2u(n[1][2]), h2u(n[1][3])};
  ws[L3MF + r3 * 8192 + b0]       = M[0];
  ws[L3MF + r3 * 8192 + b0 + 128] = M[1];
}

// ===================== K2: self-prep + layers 4..7 + root, k-parallel =====================
__device__ __forceinline__ float macTd(const uint4* __restrict__ Wr, int myk,
                                       const float* na, const half2v* nbpk) {
  float s = 0.f;
  #pragma unroll
  for (int i = 0; i < 8; ++i) {
    const uint4 w = Wr[myk * 8 + ((i ^ myk) & 7)];
    float T = dd(nbpk[0], u2h(w.x), 0.f);
    T = dd(nbpk[1], u2h(w.y), T);
    T = dd(nbpk[2], u2h(w.z), T);
    T = dd(nbpk[3], u2h(w.w), T);
    s = fmaf(na[i], T, s);
  }
  return s;
}

__global__ __launch_bounds__(NTH) void spn_c(
    const float* __restrict__ w4, const float* __restrict__ w5,
    const float* __restrict__ w6, const float* __restrict__ w7,
    const float* __restrict__ root_w,
    float* __restrict__ ws,
    float* __restrict__ out)
{
  __shared__ float stage[7680];   // 15 regions x 512 f32 = 30 KB
  __shared__ uint4 wsh4[960];     // 15 regions x 64 uint4 = 15 KB (transposed+swizzled)
  __shared__ float ssh[8];
  const int tid = threadIdx.x;

  #pragma unroll
  for (int i = 0; i < 30; ++i) {
    const int idx = tid + 256 * i;
    const int reg = idx >> 9, off = idx & 511;
    const float* src;
    if (reg < 8)       src = w4 + reg * 512;
    else if (reg < 12) src = w5 + (reg - 8) * 512;
    else if (reg < 14) src = w6 + (reg - 12) * 512;
    else               src = w7;
    stage[idx] = src[off];
  }
  if (tid == 255) {
    float m = -3.0e38f;
    for (int k = 0; k < 8; ++k) m = fmaxf(m, root_w[k]);
    float e[8]; float t = 0.f;
    for (int k = 0; k < 8; ++k) { e[k] = __expf(root_w[k] - m); t += e[k]; }
    const float inv = 1.0f / t;
    for (int k = 0; k < 8; ++k) ssh[k] = e[k] * inv;
  }
  __syncthreads();

  if (tid < 120) {
    // transposed [k][i][jp] packed with XOR-swizzled i-chunks
    const int reg = tid >> 3, k = tid & 7;
    float v[64];
    float m = -3.0e38f;
    #pragma unroll
    for (int c = 0; c < 64; ++c) { v[c] = stage[reg * 512 + c * 8 + k]; m = fmaxf(m, v[c]); }
    float t = 0.f;
    #pragma unroll
    for (int c = 0; c < 64; ++c) { v[c] = __expf(v[c] - m); t += v[c]; }
    const float inv = 1.0f / t;
    unsigned* wdwL = reinterpret_cast<unsigned*>(wsh4);
    #pragma unroll
    for (int i = 0; i < 8; ++i)
      #pragma unroll
      for (int jp = 0; jp < 4; ++jp)
        wdwL[reg * 256 + k * 32 + (((i ^ k) & 7) << 2) + jp] =
            h2u(pkrtz(v[i * 8 + 2 * jp] * inv, v[i * 8 + 2 * jp + 1] * inv));
  }
  __syncthreads();

  const int lane = tid & 63, wid = tid >> 6;
  const int myk = lane & 7, bsub = lane >> 3, gbase = lane & 56;
  const int b = blockIdx.x * 32 + wid * 8 + bsub;

  const uint4* n4 = reinterpret_cast<const uint4*>(ws);

  // ---- layer 4: 8 regions
  float n4v[8], M4[8];
  #pragma unroll
  for (int r = 0; r < 8; ++r) {
    const uint4 pa = n4[(2 * r + 0) * 8192 + b];
    const uint4 pb = n4[(2 * r + 1) * 8192 + b];
    const float Ma = ws[L3MF + (2 * r + 0) * 8192 + b];
    const float Mb = ws[L3MF + (2 * r + 1) * 8192 + b];
    float na[8];
    const half2v a0 = u2h(pa.x), a1 = u2h(pa.y), a2 = u2h(pa.z), a3 = u2h(pa.w);
    na[0] = (float)a0[0]; na[1] = (float)a0[1];
    na[2] = (float)a1[0]; na[3] = (float)a1[1];
    na[4] = (float)a2[0]; na[5] = (float)a2[1];
    na[6] = (float)a3[0]; na[7] = (float)a3[1];
    half2v nbpk[4] = {u2h(pb.x), u2h(pb.y), u2h(pb.z), u2h(pb.w)};
    float s = macTd(wsh4 + r * 64, myk, na, nbpk);
    float m = s;
    m = fmaxf(m, __shfl_xor(m, 1)); m = fmaxf(m, __shfl_xor(m, 2)); m = fmaxf(m, __shfl_xor(m, 4));
    n4v[r] = s / m;
    M4[r] = Ma + Mb + __logf(m);
  }

  // ---- layer 5: 4 regions
  float n5v[4], M5[4];
  #pragma unroll
  for (int r = 0; r < 4; ++r) {
    float na[8]; half2v nbpk[4];
    #pragma unroll
    for (int i = 0; i < 8; ++i) na[i] = __shfl(n4v[2 * r], gbase + i, 64);
    #pragma unroll
    for (int p = 0; p < 4; ++p)
      nbpk[p] = pkrtz(__shfl(n4v[2 * r + 1], gbase + 2 * p, 64),
                      __shfl(n4v[2 * r + 1], gbase + 2 * p + 1, 64));
    float s = macTd(wsh4 + (8 + r) * 64, myk, na, nbpk);
    float m = s;
    m = fmaxf(m, __shfl_xor(m, 1)); m = fmaxf(m, __shfl_xor(m, 2)); m = fmaxf(m, __shfl_xor(m, 4));
    n5v[r] = s / m;
    M5[r] = M4[2 * r] + M4[2 * r + 1] + __logf(m);
  }

  // ---- layer 6: 2 regions
  float n6v[2], M6[2];
  #pragma unroll
  for (int r = 0; r < 2; ++r) {
    float na[8]; half2v nbpk[4];
    #pragma unroll
    for (int i = 0; i < 8; ++i) na[i] = __shfl(n5v[2 * r], gbase + i, 64);
    #pragma unroll
    for (int p = 0; p < 4; ++p)
      nbpk[p] = pkrtz(__shfl(n5v[2 * r + 1], gbase + 2 * p, 64),
                      __shfl(n5v[2 * r + 1], gbase + 2 * p + 1, 64));
    float s = macTd(wsh4 + (12 + r) * 64, myk, na, nbpk);
    float m = s;
    m = fmaxf(m, __shfl_xor(m, 1)); m = fmaxf(m, __shfl_xor(m, 2)); m = fmaxf(m, __shfl_xor(m, 4));
    n6v[r] = s / m;
    M6[r] = M5[2 * r] + M5[2 * r + 1] + __logf(m);
  }

  // ---- layer 7 + root
  {
    float na[8]; half2v nbpk[4];
    #pragma unroll
    for (int i = 0; i < 8; ++i) na[i] = __shfl(n6v[0], gbase + i, 64);
    #pragma unroll
    for (int p = 0; p < 4; ++p)
      nbpk[p] = pkrtz(__shfl(n6v[1], gbase + 2 * p, 64),
                      __shfl(n6v[1], gbase + 2 * p + 1, 64));
    float s = macTd(wsh4 + 14 * 64, myk, na, nbpk);
    float m = s;
    m = fmaxf(m, __shfl_xor(m, 1)); m = fmaxf(m, __shfl_xor(m, 2)); m = fmaxf(m, __shfl_xor(m, 4));
    const float n7 = s / m;
    const float M7 = M6[0] + M6[1] + __logf(m);
    float prod = n7 * ssh[myk];
    prod += __shfl_xor(prod, 1); prod += __shfl_xor(prod, 2); prod += __shfl_xor(prod, 4);
    if (myk == 0) out[b] = M7 + __logf(prod);
  }
}

// ===================== fallback path (R1 kernel, proven 145us) =====================
static constexpr int NW   = 130560;
static constexpr int AOFF = NW;
static constexpr int BOFF = NW + 2048;
static constexpr int ROFF = NW + 4096;

__device__ __forceinline__ void leaf_eval(float xv, const float* mu8, const float* A8,
                                          const float* B8, float* n, float* M) {
  float h[8];
  float m = -3.0e38f;
  #pragma unroll
  for (int k = 0; k < 8; ++k) {
    const float z = (xv - mu8[k]) * A8[k];
    h[k] = fmaf(-0.5f * z, z, B8[k]);
    m = fmaxf(m, h[k]);
  }
  #pragma unroll
  for (int k = 0; k < 8; ++k) n[k] = __expf(h[k] - m);
  *M = m;
}

__global__ __launch_bounds__(256) void spn_prep(
    const float* __restrict__ ls,
    const float* __restrict__ w0, const float* __restrict__ w1,
    const float* __restrict__ w2, const float* __restrict__ w3,
    const float* __restrict__ w4, const float* __restrict__ w5,
    const float* __restrict__ w6, const float* __restrict__ w7,
    const float* __restrict__ root_w,
    float* __restrict__ ws)
{
  const int job = blockIdx.x * blockDim.x + threadIdx.x;
  if (job < 2040) {
    const float* wl[8] = {w0, w1, w2, w3, w4, w5, w6, w7};
    int j = job, l = 0, base = 0, R = 128;
    while (j >= R * 8) { j -= R * 8; base += R * 512; R >>= 1; ++l; }
    const int r = j >> 3, k = j & 7;
    const float* src = wl[l] + r * 512 + k;
    float v[64];
    float m = -3.0e38f;
    #pragma unroll
    for (int c = 0; c < 64; ++c) { v[c] = src[c * 8]; m = fmaxf(m, v[c]); }
    float ssum = 0.f;
    #pragma unroll
    for (int c = 0; c < 64; ++c) { v[c] = __expf(v[c] - m); ssum += v[c]; }
    const float inv = 1.0f / ssum;
    float* dst = ws + base + r * 512 + k;
    #pragma unroll
    for (int c = 0; c < 64; ++c) dst[c * 8] = v[c] * inv;
  } else if (job < 2040 + 2048) {
    const int i = job - 2040;
    const float l = ls[i];
    ws[AOFF + i] = __expf(-l);
    ws[BOFF + i] = -l - HLP;
  } else if (job == 2040 + 2048) {
    float m = -3.0e38f;
    for (int k = 0; k < 8; ++k) m = fmaxf(m, root_w[k]);
    float e[8]; float ssum = 0.f;
    for (int k = 0; k < 8; ++k) { e[k] = __expf(root_w[k] - m); ssum += e[k]; }
    const float inv = 1.0f / ssum;
    for (int k = 0; k < 8; ++k) ws[ROFF + k] = e[k] * inv;
  }
}

__device__ __forceinline__ void mac64(const float* __restrict__ Wr,
                                      const float* na, const float* nb,
                                      float* s) {
  #pragma unroll
  for (int k = 0; k < 8; ++k) s[k] = 0.f;
  #pragma unroll
  for (int i = 0; i < 8; ++i) {
    const float ai = na[i];
    #pragma unroll
    for (int j = 0; j < 8; ++j) {
      const float e = ai * nb[j];
      const float4 wA = *reinterpret_cast<const float4*>(Wr + (i * 8 + j) * 8);
      const float4 wB = *reinterpret_cast<const float4*>(Wr + (i * 8 + j) * 8 + 4);
      s[0] = fmaf(e, wA.x, s[0]); s[1] = fmaf(e, wA.y, s[1]);
      s[2] = fmaf(e, wA.z, s[2]); s[3] = fmaf(e, wA.w, s[3]);
      s[4] = fmaf(e, wB.x, s[4]); s[5] = fmaf(e, wB.y, s[5]);
      s[6] = fmaf(e, wB.z, s[6]); s[7] = fmaf(e, wB.w, s[7]);
    }
  }
}

#define TB 8
static constexpr int PLA = 128 * 9 + 5;
static constexpr int PLB = 64 * 9 + 5;
static constexpr int NAO = 0;
static constexpr int NBO = TB * PLA;
static constexpr int MAO = NBO + TB * PLB;
static constexpr int MBO = MAO + TB * 128;
static constexpr int SMEM_F = MBO + TB * 64;

__global__ __launch_bounds__(NTH, 2) void spn_main_fb(
    const float* __restrict__ x,
    const float* __restrict__ mu,
    const float* __restrict__ ws,
    float* __restrict__ out)
{
  const float* leafA = ws + AOFF;
  const float* leafB = ws + BOFF;
  const float* srw   = ws + ROFF;

  __shared__ float smem[SMEM_F];

  const int tid = threadIdx.x;
  const int bB = blockIdx.x * TB;

  {
    const float* W0 = ws;
    for (int it = tid; it < TB * 128; it += NTH) {
      const int bb = it & (TB - 1), r = it >> 3;
      float na[8], nb[8], Ma, Mb;
      const int f0 = 2 * r;
      const float xv0 = x[(bB + bb) * 256 + f0];
      const float xv1 = x[(bB + bb) * 256 + f0 + 1];
      leaf_eval(xv0, mu + f0 * 8, leafA + f0 * 8, leafB + f0 * 8, na, &Ma);
      leaf_eval(xv1, mu + f0 * 8 + 8, leafA + f0 * 8 + 8, leafB + f0 * 8 + 8, nb, &Mb);
      float s[8];
      mac64(W0 + r * 512, na, nb, s);
      const float smax = max8(s);
      const float inv = 1.0f / smax;
      const int ob = NAO + bb * PLA + r * 9;
      #pragma unroll
      for (int k = 0; k < 8; ++k) smem[ob + k] = s[k] * inv;
      smem[MAO + bb * 128 + r] = Ma + Mb + __logf(smax);
    }
  }
  __syncthreads();

  int pinO = NAO, poutO = NBO;
  int MinO = MAO, MoutO = MBO;
  int PLIN = PLA, PLOUT = PLB;
  int Rin = 128;
  const float* Wl = ws + 128 * 512;
  for (int l = 1; l < 7; ++l) {
    const int Rout = Rin >> 1;
    for (int it = tid; it < TB * Rout; it += NTH) {
      const int bb = it & (TB - 1), r = it >> 3;
      float na[8], nb[8];
      const int ia = pinO + bb * PLIN + (2 * r) * 9;
      #pragma unroll
      for (int i = 0; i < 8; ++i) { na[i] = smem[ia + i]; nb[i] = smem[ia + 9 + i]; }
      float s[8];
      mac64(Wl + r * 512, na, nb, s);
      const float smax = max8(s);
      const float inv = 1.0f / smax;
      const int ob = poutO + bb * PLOUT + r * 9;
      #pragma unroll
      for (int k = 0; k < 8; ++k) smem[ob + k] = s[k] * inv;
      smem[MoutO + bb * Rout + r] =
          smem[MinO + bb * Rin + 2 * r] + smem[MinO + bb * Rin + 2 * r + 1] + __logf(smax);
    }
    __syncthreads();
    int t;
    t = pinO; pinO = poutO; poutO = t;
    t = MinO; MinO = MoutO; MoutO = t;
    t = PLIN; PLIN = PLOUT; PLOUT = t;
    Rin = Rout;
    Wl += Rout * 512;
  }

  for (int it = tid; it < TB; it += NTH) {
    const int bb = it;
    float na[8], nb[8];
    const int ia = pinO + bb * PLIN;
    #pragma unroll
    for (int i = 0; i < 8; ++i) { na[i] = smem[ia + i]; nb[i] = smem[ia + 9 + i]; }
    float s[8];
    mac64(Wl, na, nb, s);
    float acc = 0.f;
    #pragma unroll
    for (int k = 0; k < 8; ++k) acc = fmaf(s[k], srw[k], acc);
    out[bB + bb] = smem[MinO + bb * 2] + smem[MinO + bb * 2 + 1] + __logf(acc);
  }
}

extern "C" void kernel_launch(void* const* d_in, const int* in_sizes, int n_in,
                              void* d_out, int out_size, void* d_ws, size_t ws_size,
                              hipStream_t stream) {
  (void)in_sizes; (void)n_in; (void)out_size;
  const float* x      = (const float*)d_in[0];
  const float* mu     = (const float*)d_in[1];
  const float* ls     = (const float*)d_in[2];
  const float* w0     = (const float*)d_in[3];
  const float* w1     = (const float*)d_in[4];
  const float* w2     = (const float*)d_in[5];
  const float* w3     = (const float*)d_in[6];
  const float* w4     = (const float*)d_in[7];
  const float* w5     = (const float*)d_in[8];
  const float* w6     = (const float*)d_in[9];
  const float* w7     = (const float*)d_in[10];
  const float* root_w = (const float*)d_in[11];
  float* ws  = (float*)d_ws;
  float* out = (float*)d_out;

  if (ws_size >= WS_NEED_B) {
    spn_ab2<<<512, 128, 0, stream>>>(x, mu, ls, w0, w1, w2, w3, ws);
    spn_c<<<256, NTH, 0, stream>>>(w4, w5, w6, w7, root_w, ws, out);
  } else {
    spn_prep<<<16, 256, 0, stream>>>(ls, w0, w1, w2, w3, w4, w5, w6, w7, root_w, ws);
    spn_main_fb<<<8192 / TB, NTH, 0, stream>>>(x, mu, ws, out);
  }
}

// Round 11
// 53.987 us; speedup vs baseline: 1.3280x; 1.3280x over previous
//
#include <hip/hip_runtime.h>
#include <math.h>

#define NTH 256

static constexpr float HLP = 0.9189385332046727f; // 0.5*log(2*pi)

typedef __attribute__((ext_vector_type(2))) _Float16 half2v;
typedef __attribute__((ext_vector_type(2))) __fp16   fp16x2;

// ===================== main-path ws layout =====================
// [0, 1048576)          L2 n f16-packed uint4 [32][8192]  (uint4 idx rr*8192+b)
// [1048576, 1310720)    L2 M f32 [32][8192]
static constexpr int L2MF = 1048576;
static constexpr size_t WS_NEED_B = (size_t)1310720 * 4;   // 5.24 MB

// ===================== helpers =====================
__device__ __forceinline__ half2v pkrtz(float a, float b) {
  return __builtin_bit_cast(half2v, __builtin_amdgcn_cvt_pkrtz(a, b));
}
__device__ __forceinline__ half2v u2h(unsigned u) {
  return __builtin_bit_cast(half2v, u);
}
__device__ __forceinline__ unsigned h2u(half2v h) {
  return __builtin_bit_cast(unsigned, h);
}
__device__ __forceinline__ float dd(half2v a, half2v b, float c) {
#if __has_builtin(__builtin_amdgcn_fdot2)
  return __builtin_amdgcn_fdot2(__builtin_bit_cast(fp16x2, a),
                                __builtin_bit_cast(fp16x2, b), c, false);
#else
  return fmaf((float)a[0], (float)b[0], fmaf((float)a[1], (float)b[1], c));
#endif
}
__device__ __forceinline__ float max8(const float* s) {
  float m = s[0];
  #pragma unroll
  for (int k = 1; k < 8; ++k) m = fmaxf(m, s[k]);
  return m;
}

__device__ __forceinline__ void leaf_ii(float xv, const float* mu8, const float* A8,
                                        const float* B8, half2v* ii, float* M) {
  float h[8];
  float m = -3.0e38f;
  #pragma unroll
  for (int k = 0; k < 8; ++k) {
    const float z = (xv - mu8[k]) * A8[k];
    h[k] = fmaf(-0.5f * z, z, B8[k]);
    m = fmaxf(m, h[k]);
  }
  #pragma unroll
  for (int k = 0; k < 8; ++k) {
    const float n = __expf(h[k] - m);
    ii[k] = pkrtz(n, n);
  }
  *M = m;
}
__device__ __forceinline__ void leaf_pk(float xv, const float* mu8, const float* A8,
                                        const float* B8, half2v* pk, float* M) {
  float h[8];
  float m = -3.0e38f;
  #pragma unroll
  for (int k = 0; k < 8; ++k) {
    const float z = (xv - mu8[k]) * A8[k];
    h[k] = fmaf(-0.5f * z, z, B8[k]);
    m = fmaxf(m, h[k]);
  }
  #pragma unroll
  for (int p = 0; p < 4; ++p) {
    const float n0 = __expf(h[2 * p] - m);
    const float n1 = __expf(h[2 * p + 1] - m);
    pk[p] = pkrtz(n0, n1);
  }
  *M = m;
}

// combine via dot2: s[k] = sum_{i,j} na_i nb_j W[i*8+j][k]
template<int G, bool OUT_II>
__device__ __forceinline__ void combine_d2(const uint4* __restrict__ WL,
                                           const half2v (&na)[G][8],
                                           const half2v (&nb)[G][4],
                                           half2v (&oii)[G][8],
                                           half2v (&opk)[G][4],
                                           float (&M)[G]) {
  float s[G][8];
  #pragma unroll
  for (int g = 0; g < G; ++g)
    #pragma unroll
    for (int k = 0; k < 8; ++k) s[g][k] = 0.f;

  #pragma unroll
  for (int i = 0; i < 8; ++i) {
    half2v e[G][4];
    #pragma unroll
    for (int g = 0; g < G; ++g) {
      e[g][0] = na[g][i] * nb[g][0];
      e[g][1] = na[g][i] * nb[g][1];
      e[g][2] = na[g][i] * nb[g][2];
      e[g][3] = na[g][i] * nb[g][3];
    }
    #pragma unroll
    for (int k = 0; k < 8; ++k) {
      const uint4 w = WL[i * 8 + k];
      #pragma unroll
      for (int g = 0; g < G; ++g) {
        float acc = s[g][k];
        acc = dd(e[g][0], u2h(w.x), acc);
        acc = dd(e[g][1], u2h(w.y), acc);
        acc = dd(e[g][2], u2h(w.z), acc);
        acc = dd(e[g][3], u2h(w.w), acc);
        s[g][k] = acc;
      }
    }
  }
  #pragma unroll
  for (int g = 0; g < G; ++g) {
    const float smax = max8(s[g]);
    const float inv = 1.0f / smax;
    if constexpr (OUT_II) {
      #pragma unroll
      for (int p = 0; p < 8; ++p) {
        const float n = s[g][p] * inv;
        oii[g][p] = pkrtz(n, n);
      }
    } else {
      #pragma unroll
      for (int p = 0; p < 4; ++p)
        opk[g][p] = pkrtz(s[g][2 * p] * inv, s[g][2 * p + 1] * inv);
    }
    M[g] += __logf(smax);
  }
}

// block-local softmax of one column (r,k) from stage into packed [c][k]-pair layout
__device__ __forceinline__ void prep_col_std(const float* stage, unsigned* wdwL,
                                             int r, int k) {
  float v[64];
  float m = -3.0e38f;
  #pragma unroll
  for (int c = 0; c < 64; ++c) { v[c] = stage[r * 512 + c * 8 + k]; m = fmaxf(m, v[c]); }
  float t = 0.f;
  #pragma unroll
  for (int c = 0; c < 64; ++c) { v[c] = __expf(v[c] - m); t += v[c]; }
  const float inv = 1.0f / t;
  #pragma unroll
  for (int i = 0; i < 8; ++i)
    #pragma unroll
    for (int jp = 0; jp < 4; ++jp)
      wdwL[r * 256 + (i * 8 + k) * 4 + jp] =
          h2u(pkrtz(v[i * 8 + 2 * jp] * inv, v[i * 8 + 2 * jp + 1] * inv));
}

// one subtree (2x L0 + L1) for G=2 batches; half-block weight layout:
// L0 slots 0..3, L1 slots 4..5. lsh: [0..63] mu, [64..127] A, [128..191] B (8 features)
template<bool OUT_II>
__device__ __forceinline__ void subtree2b(const uint4* __restrict__ wsh4, int sub,
                                          const float* lsh, float4 xa, float4 xb,
                                          half2v (&oii)[2][8], half2v (&opk)[2][4],
                                          float (&Mout)[2]) {
  half2v ii[2][8], pk[2][4];
  half2v aii[2][8], bpk[2][4];
  half2v dii[2][8], dpk[2][4];
  float Ma, Mb;
  const int fl = 4 * sub;
  const float* m0 = lsh + fl * 8;
  const float* A0 = lsh + 64 + fl * 8;
  const float* B0 = lsh + 128 + fl * 8;

  leaf_ii(xa.x, m0,      A0,      B0,      ii[0], &Ma);
  leaf_pk(xa.y, m0 + 8,  A0 + 8,  B0 + 8,  pk[0], &Mb);
  float MA[2];
  MA[0] = Ma + Mb;
  leaf_ii(xb.x, m0,      A0,      B0,      ii[1], &Ma);
  leaf_pk(xb.y, m0 + 8,  A0 + 8,  B0 + 8,  pk[1], &Mb);
  MA[1] = Ma + Mb;
  combine_d2<2, true>(wsh4 + (2 * sub) * 64, ii, pk, aii, dpk, MA);

  leaf_ii(xa.z, m0 + 16, A0 + 16, B0 + 16, ii[0], &Ma);
  leaf_pk(xa.w, m0 + 24, A0 + 24, B0 + 24, pk[0], &Mb);
  float MB[2];
  MB[0] = Ma + Mb;
  leaf_ii(xb.z, m0 + 16, A0 + 16, B0 + 16, ii[1], &Ma);
  leaf_pk(xb.w, m0 + 24, A0 + 24, B0 + 24, pk[1], &Mb);
  MB[1] = Ma + Mb;
  combine_d2<2, false>(wsh4 + (2 * sub + 1) * 64, ii, pk, dii, bpk, MB);

  float M[2] = {MA[0] + MB[0], MA[1] + MB[1]};
  combine_d2<2, OUT_II>(wsh4 + (4 + sub) * 64, aii, bpk, oii, opk, M);
  Mout[0] = M[0];
  Mout[1] = M[1];
}

// ===================== K1: half-subtree L0..L2, G=2, 256 thr =====================
// grid: 32 (r3,half) x 16 chunks = 512 blocks; thread = 2 batches (b0, b0+256)
__global__ __launch_bounds__(NTH, 2) void spn_k1(
    const float* __restrict__ x,
    const float* __restrict__ mu,
    const float* __restrict__ ls,
    const float* __restrict__ w0, const float* __restrict__ w1,
    const float* __restrict__ w2,
    float* __restrict__ ws)
{
  __shared__ float stage[3584];   // 7 regions x 512 f32 = 14 KB
  __shared__ uint4 wsh4[448];     // 7 regions x 64 uint4 = 7 KB packed f16
  __shared__ float lsh[192];      // mu/A/B for 8 features x 8
  const int tid = threadIdx.x;
  const int rh = blockIdx.x >> 4;          // (r3, half) in [0,32)
  const int chunk = blockIdx.x & 15;
  const int r3 = rh >> 1, h = rh & 1;

  // stage raw weights for this half-block's 7 regions (coalesced)
  #pragma unroll
  for (int i = 0; i < 14; ++i) {
    const int idx = tid + 256 * i;
    const int reg = idx >> 9, off = idx & 511;
    const float* src;
    if (reg < 4)      src = w0 + (8 * r3 + 4 * h + reg) * 512;
    else if (reg < 6) src = w1 + (4 * r3 + 2 * h + (reg - 4)) * 512;
    else              src = w2 + (2 * r3 + h) * 512;
    stage[idx] = src[off];
  }
  if (tid < 64) {
    const int base = 128 * r3 + 64 * h;   // 8 features x 8
    const float l = ls[base + tid];
    lsh[tid]       = mu[base + tid];
    lsh[64 + tid]  = __expf(-l);
    lsh[128 + tid] = -l - HLP;
  }
  __syncthreads();

  if (tid < 56) prep_col_std(stage, reinterpret_cast<unsigned*>(wsh4), tid >> 3, tid & 7);
  __syncthreads();

  const int b0 = chunk * 512 + tid;          // batches b0, b0+256
  const float* xa = x + (size_t)b0 * 256 + 16 * r3 + 8 * h;
  const float* xb = x + (size_t)(b0 + 256) * 256 + 16 * r3 + 8 * h;
  const float4 xa0 = *reinterpret_cast<const float4*>(xa);
  const float4 xa1 = *reinterpret_cast<const float4*>(xa + 4);
  const float4 xb0 = *reinterpret_cast<const float4*>(xb);
  const float4 xb1 = *reinterpret_cast<const float4*>(xb + 4);

  half2v s0ii[2][8], s1pk[2][4];
  half2v dii[2][8], dpk[2][4];
  float M0[2], M1[2];

  subtree2b<true >(wsh4, 0, lsh, xa0, xb0, s0ii, dpk, M0);
  subtree2b<false>(wsh4, 1, lsh, xa1, xb1, dii, s1pk, M1);

  float M[2] = {M0[0] + M1[0], M0[1] + M1[1]};
  half2v n[2][4];
  combine_d2<2, false>(wsh4 + 6 * 64, s0ii, s1pk, dii, n, M);

  uint4* outn = reinterpret_cast<uint4*>(ws);
  outn[rh * 8192 + b0] =
      uint4{h2u(n[0][0]), h2u(n[0][1]), h2u(n[0][2]), h2u(n[0][3])};
  outn[rh * 8192 + b0 + 256] =
      uint4{h2u(n[1][0]), h2u(n[1][1]), h2u(n[1][2]), h2u(n[1][3])};
  ws[L2MF + rh * 8192 + b0]       = M[0];
  ws[L2MF + rh * 8192 + b0 + 256] = M[1];
}

// ===================== K2: self-prep + layers 3..7 + root, k-parallel =====================
// weight slots: L3 r0..15 -> 0..15 | L4 -> 16..23 | L5 -> 24..27 | L6 -> 28..29 | L7 -> 30
__device__ __forceinline__ float macTd(const uint4* __restrict__ Wr, int myk,
                                       const float* na, const half2v* nbpk) {
  float s = 0.f;
  #pragma unroll
  for (int i = 0; i < 8; ++i) {
    const uint4 w = Wr[myk * 8 + ((i ^ myk) & 7)];
    float T = dd(nbpk[0], u2h(w.x), 0.f);
    T = dd(nbpk[1], u2h(w.y), T);
    T = dd(nbpk[2], u2h(w.z), T);
    T = dd(nbpk[3], u2h(w.w), T);
    s = fmaf(na[i], T, s);
  }
  return s;
}

__global__ __launch_bounds__(NTH) void spn_c2(
    const float* __restrict__ w3,
    const float* __restrict__ w4, const float* __restrict__ w5,
    const float* __restrict__ w6, const float* __restrict__ w7,
    const float* __restrict__ root_w,
    float* __restrict__ ws,
    float* __restrict__ out)
{
  __shared__ float stage[15872];  // 31 regions x 512 f32 = 62 KB
  __shared__ uint4 wsh4[1984];    // 31 regions x 64 uint4 = 31 KB (transposed+swizzled)
  __shared__ float ssh[8];
  const int tid = threadIdx.x;

  #pragma unroll
  for (int i = 0; i < 62; ++i) {
    const int idx = tid + 256 * i;
    const int reg = idx >> 9, off = idx & 511;
    const float* src;
    if (reg < 16)      src = w3 + reg * 512;
    else if (reg < 24) src = w4 + (reg - 16) * 512;
    else if (reg < 28) src = w5 + (reg - 24) * 512;
    else if (reg < 30) src = w6 + (reg - 28) * 512;
    else               src = w7;
    stage[idx] = src[off];
  }
  if (tid == 255) {
    float m = -3.0e38f;
    for (int k = 0; k < 8; ++k) m = fmaxf(m, root_w[k]);
    float e[8]; float t = 0.f;
    for (int k = 0; k < 8; ++k) { e[k] = __expf(root_w[k] - m); t += e[k]; }
    const float inv = 1.0f / t;
    for (int k = 0; k < 8; ++k) ssh[k] = e[k] * inv;
  }
  __syncthreads();

  if (tid < 248) {
    // transposed [k][i][jp] packed with XOR-swizzled i-chunks
    const int reg = tid >> 3, k = tid & 7;
    float v[64];
    float m = -3.0e38f;
    #pragma unroll
    for (int c = 0; c < 64; ++c) { v[c] = stage[reg * 512 + c * 8 + k]; m = fmaxf(m, v[c]); }
    float t = 0.f;
    #pragma unroll
    for (int c = 0; c < 64; ++c) { v[c] = __expf(v[c] - m); t += v[c]; }
    const float inv = 1.0f / t;
    unsigned* wdwL = reinterpret_cast<unsigned*>(wsh4);
    #pragma unroll
    for (int i = 0; i < 8; ++i)
      #pragma unroll
      for (int jp = 0; jp < 4; ++jp)
        wdwL[reg * 256 + k * 32 + (((i ^ k) & 7) << 2) + jp] =
            h2u(pkrtz(v[i * 8 + 2 * jp] * inv, v[i * 8 + 2 * jp + 1] * inv));
  }
  __syncthreads();

  const int lane = tid & 63, wid = tid >> 6;
  const int myk = lane & 7, bsub = lane >> 3, gbase = lane & 56;
  const int b = blockIdx.x * 32 + wid * 8 + bsub;

  const uint4* n4 = reinterpret_cast<const uint4*>(ws);

  // ---- layer 3: 16 regions from the 32 stored L2 regions
  float n3v[16], M3[16];
  #pragma unroll
  for (int r = 0; r < 16; ++r) {
    const uint4 pa = n4[(2 * r + 0) * 8192 + b];
    const uint4 pb = n4[(2 * r + 1) * 8192 + b];
    const float Ma = ws[L2MF + (2 * r + 0) * 8192 + b];
    const float Mb = ws[L2MF + (2 * r + 1) * 8192 + b];
    float na[8];
    const half2v a0 = u2h(pa.x), a1 = u2h(pa.y), a2 = u2h(pa.z), a3 = u2h(pa.w);
    na[0] = (float)a0[0]; na[1] = (float)a0[1];
    na[2] = (float)a1[0]; na[3] = (float)a1[1];
    na[4] = (float)a2[0]; na[5] = (float)a2[1];
    na[6] = (float)a3[0]; na[7] = (float)a3[1];
    half2v nbpk[4] = {u2h(pb.x), u2h(pb.y), u2h(pb.z), u2h(pb.w)};
    float s = macTd(wsh4 + r * 64, myk, na, nbpk);
    float m = s;
    m = fmaxf(m, __shfl_xor(m, 1)); m = fmaxf(m, __shfl_xor(m, 2)); m = fmaxf(m, __shfl_xor(m, 4));
    n3v[r] = s / m;
    M3[r] = Ma + Mb + __logf(m);
  }

  // ---- layer 4: 8 regions
  float n4v[8], M4[8];
  #pragma unroll
  for (int r = 0; r < 8; ++r) {
    float na[8]; half2v nbpk[4];
    #pragma unroll
    for (int i = 0; i < 8; ++i) na[i] = __shfl(n3v[2 * r], gbase + i, 64);
    #pragma unroll
    for (int p = 0; p < 4; ++p)
      nbpk[p] = pkrtz(__shfl(n3v[2 * r + 1], gbase + 2 * p, 64),
                      __shfl(n3v[2 * r + 1], gbase + 2 * p + 1, 64));
    float s = macTd(wsh4 + (16 + r) * 64, myk, na, nbpk);
    float m = s;
    m = fmaxf(m, __shfl_xor(m, 1)); m = fmaxf(m, __shfl_xor(m, 2)); m = fmaxf(m, __shfl_xor(m, 4));
    n4v[r] = s / m;
    M4[r] = M3[2 * r] + M3[2 * r + 1] + __logf(m);
  }

  // ---- layer 5: 4 regions
  float n5v[4], M5[4];
  #pragma unroll
  for (int r = 0; r < 4; ++r) {
    float na[8]; half2v nbpk[4];
    #pragma unroll
    for (int i = 0; i < 8; ++i) na[i] = __shfl(n4v[2 * r], gbase + i, 64);
    #pragma unroll
    for (int p = 0; p < 4; ++p)
      nbpk[p] = pkrtz(__shfl(n4v[2 * r + 1], gbase + 2 * p, 64),
                      __shfl(n4v[2 * r + 1], gbase + 2 * p + 1, 64));
    float s = macTd(wsh4 + (24 + r) * 64, myk, na, nbpk);
    float m = s;
    m = fmaxf(m, __shfl_xor(m, 1)); m = fmaxf(m, __shfl_xor(m, 2)); m = fmaxf(m, __shfl_xor(m, 4));
    n5v[r] = s / m;
    M5[r] = M4[2 * r] + M4[2 * r + 1] + __logf(m);
  }

  // ---- layer 6: 2 regions
  float n6v[2], M6[2];
  #pragma unroll
  for (int r = 0; r < 2; ++r) {
    float na[8]; half2v nbpk[4];
    #pragma unroll
    for (int i = 0; i < 8; ++i) na[i] = __shfl(n5v[2 * r], gbase + i, 64);
    #pragma unroll
    for (int p = 0; p < 4; ++p)
      nbpk[p] = pkrtz(__shfl(n5v[2 * r + 1], gbase + 2 * p, 64),
                      __shfl(n5v[2 * r + 1], gbase + 2 * p + 1, 64));
    float s = macTd(wsh4 + (28 + r) * 64, myk, na, nbpk);
    float m = s;
    m = fmaxf(m, __shfl_xor(m, 1)); m = fmaxf(m, __shfl_xor(m, 2)); m = fmaxf(m, __shfl_xor(m, 4));
    n6v[r] = s / m;
    M6[r] = M5[2 * r] + M5[2 * r + 1] + __logf(m);
  }

  // ---- layer 7 + root
  {
    float na[8]; half2v nbpk[4];
    #pragma unroll
    for (int i = 0; i < 8; ++i) na[i] = __shfl(n6v[0], gbase + i, 64);
    #pragma unroll
    for (int p = 0; p < 4; ++p)
      nbpk[p] = pkrtz(__shfl(n6v[1], gbase + 2 * p, 64),
                      __shfl(n6v[1], gbase + 2 * p + 1, 64));
    float s = macTd(wsh4 + 30 * 64, myk, na, nbpk);
    float m = s;
    m = fmaxf(m, __shfl_xor(m, 1)); m = fmaxf(m, __shfl_xor(m, 2)); m = fmaxf(m, __shfl_xor(m, 4));
    const float n7 = s / m;
    const float M7 = M6[0] + M6[1] + __logf(m);
    float prod = n7 * ssh[myk];
    prod += __shfl_xor(prod, 1); prod += __shfl_xor(prod, 2); prod += __shfl_xor(prod, 4);
    if (myk == 0) out[b] = M7 + __logf(prod);
  }
}

// ===================== fallback path (R1 kernel, proven 145us) =====================
static constexpr int NW   = 130560;
static constexpr int AOFF = NW;
static constexpr int BOFF = NW + 2048;
static constexpr int ROFF = NW + 4096;

__device__ __forceinline__ void leaf_eval(float xv, const float* mu8, const float* A8,
                                          const float* B8, float* n, float* M) {
  float h[8];
  float m = -3.0e38f;
  #pragma unroll
  for (int k = 0; k < 8; ++k) {
    const float z = (xv - mu8[k]) * A8[k];
    h[k] = fmaf(-0.5f * z, z, B8[k]);
    m = fmaxf(m, h[k]);
  }
  #pragma unroll
  for (int k = 0; k < 8; ++k) n[k] = __expf(h[k] - m);
  *M = m;
}

__global__ __launch_bounds__(256) void spn_prep(
    const float* __restrict__ ls,
    const float* __restrict__ w0, const float* __restrict__ w1,
    const float* __restrict__ w2, const float* __restrict__ w3,
    const float* __restrict__ w4, const float* __restrict__ w5,
    const float* __restrict__ w6, const float* __restrict__ w7,
    const float* __restrict__ root_w,
    float* __restrict__ ws)
{
  const int job = blockIdx.x * blockDim.x + threadIdx.x;
  if (job < 2040) {
    const float* wl[8] = {w0, w1, w2, w3, w4, w5, w6, w7};
    int j = job, l = 0, base = 0, R = 128;
    while (j >= R * 8) { j -= R * 8; base += R * 512; R >>= 1; ++l; }
    const int r = j >> 3, k = j & 7;
    const float* src = wl[l] + r * 512 + k;
    float v[64];
    float m = -3.0e38f;
    #pragma unroll
    for (int c = 0; c < 64; ++c) { v[c] = src[c * 8]; m = fmaxf(m, v[c]); }
    float ssum = 0.f;
    #pragma unroll
    for (int c = 0; c < 64; ++c) { v[c] = __expf(v[c] - m); ssum += v[c]; }
    const float inv = 1.0f / ssum;
    float* dst = ws + base + r * 512 + k;
    #pragma unroll
    for (int c = 0; c < 64; ++c) dst[c * 8] = v[c] * inv;
  } else if (job < 2040 + 2048) {
    const int i = job - 2040;
    const float l = ls[i];
    ws[AOFF + i] = __expf(-l);
    ws[BOFF + i] = -l - HLP;
  } else if (job == 2040 + 2048) {
    float m = -3.0e38f;
    for (int k = 0; k < 8; ++k) m = fmaxf(m, root_w[k]);
    float e[8]; float ssum = 0.f;
    for (int k = 0; k < 8; ++k) { e[k] = __expf(root_w[k] - m); ssum += e[k]; }
    const float inv = 1.0f / ssum;
    for (int k = 0; k < 8; ++k) ws[ROFF + k] = e[k] * inv;
  }
}

__device__ __forceinline__ void mac64(const float* __restrict__ Wr,
                                      const float* na, const float* nb,
                                      float* s) {
  #pragma unroll
  for (int k = 0; k < 8; ++k) s[k] = 0.f;
  #pragma unroll
  for (int i = 0; i < 8; ++i) {
    const float ai = na[i];
    #pragma unroll
    for (int j = 0; j < 8; ++j) {
      const float e = ai * nb[j];
      const float4 wA = *reinterpret_cast<const float4*>(Wr + (i * 8 + j) * 8);
      const float4 wB = *reinterpret_cast<const float4*>(Wr + (i * 8 + j) * 8 + 4);
      s[0] = fmaf(e, wA.x, s[0]); s[1] = fmaf(e, wA.y, s[1]);
      s[2] = fmaf(e, wA.z, s[2]); s[3] = fmaf(e, wA.w, s[3]);
      s[4] = fmaf(e, wB.x, s[4]); s[5] = fmaf(e, wB.y, s[5]);
      s[6] = fmaf(e, wB.z, s[6]); s[7] = fmaf(e, wB.w, s[7]);
    }
  }
}

#define TB 8
static constexpr int PLA = 128 * 9 + 5;
static constexpr int PLB = 64 * 9 + 5;
static constexpr int NAO = 0;
static constexpr int NBO = TB * PLA;
static constexpr int MAO = NBO + TB * PLB;
static constexpr int MBO = MAO + TB * 128;
static constexpr int SMEM_F = MBO + TB * 64;

__global__ __launch_bounds__(NTH, 2) void spn_main_fb(
    const float* __restrict__ x,
    const float* __restrict__ mu,
    const float* __restrict__ ws,
    float* __restrict__ out)
{
  const float* leafA = ws + AOFF;
  const float* leafB = ws + BOFF;
  const float* srw   = ws + ROFF;

  __shared__ float smem[SMEM_F];

  const int tid = threadIdx.x;
  const int bB = blockIdx.x * TB;

  {
    const float* W0 = ws;
    for (int it = tid; it < TB * 128; it += NTH) {
      const int bb = it & (TB - 1), r = it >> 3;
      float na[8], nb[8], Ma, Mb;
      const int f0 = 2 * r;
      const float xv0 = x[(bB + bb) * 256 + f0];
      const float xv1 = x[(bB + bb) * 256 + f0 + 1];
      leaf_eval(xv0, mu + f0 * 8, leafA + f0 * 8, leafB + f0 * 8, na, &Ma);
      leaf_eval(xv1, mu + f0 * 8 + 8, leafA + f0 * 8 + 8, leafB + f0 * 8 + 8, nb, &Mb);
      float s[8];
      mac64(W0 + r * 512, na, nb, s);
      const float smax = max8(s);
      const float inv = 1.0f / smax;
      const int ob = NAO + bb * PLA + r * 9;
      #pragma unroll
      for (int k = 0; k < 8; ++k) smem[ob + k] = s[k] * inv;
      smem[MAO + bb * 128 + r] = Ma + Mb + __logf(smax);
    }
  }
  __syncthreads();

  int pinO = NAO, poutO = NBO;
  int MinO = MAO, MoutO = MBO;
  int PLIN = PLA, PLOUT = PLB;
  int Rin = 128;
  const float* Wl = ws + 128 * 512;
  for (int l = 1; l < 7; ++l) {
    const int Rout = Rin >> 1;
    for (int it = tid; it < TB * Rout; it += NTH) {
      const int bb = it & (TB - 1), r = it >> 3;
      float na[8], nb[8];
      const int ia = pinO + bb * PLIN + (2 * r) * 9;
      #pragma unroll
      for (int i = 0; i < 8; ++i) { na[i] = smem[ia + i]; nb[i] = smem[ia + 9 + i]; }
      float s[8];
      mac64(Wl + r * 512, na, nb, s);
      const float smax = max8(s);
      const float inv = 1.0f / smax;
      const int ob = poutO + bb * PLOUT + r * 9;
      #pragma unroll
      for (int k = 0; k < 8; ++k) smem[ob + k] = s[k] * inv;
      smem[MoutO + bb * Rout + r] =
          smem[MinO + bb * Rin + 2 * r] + smem[MinO + bb * Rin + 2 * r + 1] + __logf(smax);
    }
    __syncthreads();
    int t;
    t = pinO; pinO = poutO; poutO = t;
    t = MinO; MinO = MoutO; MoutO = t;
    t = PLIN; PLIN = PLOUT; PLOUT = t;
    Rin = Rout;
    Wl += Rout * 512;
  }

  for (int it = tid; it < TB; it += NTH) {
    const int bb = it;
    float na[8], nb[8];
    const int ia = pinO + bb * PLIN;
    #pragma unroll
    for (int i = 0; i < 8; ++i) { na[i] = smem[ia + i]; nb[i] = smem[ia + 9 + i]; }
    float s[8];
    mac64(Wl, na, nb, s);
    float acc = 0.f;
    #pragma unroll
    for (int k = 0; k < 8; ++k) acc = fmaf(s[k], srw[k], acc);
    out[bB + bb] = smem[MinO + bb * 2] + smem[MinO + bb * 2 + 1] + __logf(acc);
  }
}

extern "C" void kernel_launch(void* const* d_in, const int* in_sizes, int n_in,
                              void* d_out, int out_size, void* d_ws, size_t ws_size,
                              hipStream_t stream) {
  (void)in_sizes; (void)n_in; (void)out_size;
  const float* x      = (const float*)d_in[0];
  const float* mu     = (const float*)d_in[1];
  const float* ls     = (const float*)d_in[2];
  const float* w0     = (const float*)d_in[3];
  const float* w1     = (const float*)d_in[4];
  const float* w2     = (const float*)d_in[5];
  const float* w3     = (const float*)d_in[6];
  const float* w4     = (const float*)d_in[7];
  const float* w5     = (const float*)d_in[8];
  const float* w6     = (const float*)d_in[9];
  const float* w7     = (const float*)d_in[10];
  const float* root_w = (const float*)d_in[11];
  float* ws  = (float*)d_ws;
  float* out = (float*)d_out;

  if (ws_size >= WS_NEED_B) {
    spn_k1<<<512, NTH, 0, stream>>>(x, mu, ls, w0, w1, w2, ws);
    spn_c2<<<256, NTH, 0, stream>>>(w3, w4, w5, w6, w7, root_w, ws, out);
  } else {
    spn_prep<<<16, 256, 0, stream>>>(ls, w0, w1, w2, w3, w4, w5, w6, w7, root_w, ws);
    spn_main_fb<<<8192 / TB, NTH, 0, stream>>>(x, mu, ws, out);
  }
}

// Round 12
// 47.809 us; speedup vs baseline: 1.4996x; 1.1292x over previous
//
#include <hip/hip_runtime.h>
#include <math.h>

#define NTH 256

static constexpr float HLP = 0.9189385332046727f; // 0.5*log(2*pi)

typedef __attribute__((ext_vector_type(2))) _Float16 half2v;
typedef __attribute__((ext_vector_type(2))) __fp16   fp16x2;

// ===================== main-path ws layout =====================
// [0, 524288)        L3 n f16-packed uint4 [16][8192]  (uint4 idx r3*8192+b)
// [524288, 655360)   L3 M f32 [16][8192]
static constexpr int L3MF = 524288;
static constexpr size_t WS_NEED_B = (size_t)655360 * 4;   // 2.62 MB

// ===================== helpers =====================
__device__ __forceinline__ half2v pkrtz(float a, float b) {
  return __builtin_bit_cast(half2v, __builtin_amdgcn_cvt_pkrtz(a, b));
}
__device__ __forceinline__ half2v u2h(unsigned u) {
  return __builtin_bit_cast(half2v, u);
}
__device__ __forceinline__ unsigned h2u(half2v h) {
  return __builtin_bit_cast(unsigned, h);
}
__device__ __forceinline__ float dd(half2v a, half2v b, float c) {
#if __has_builtin(__builtin_amdgcn_fdot2)
  return __builtin_amdgcn_fdot2(__builtin_bit_cast(fp16x2, a),
                                __builtin_bit_cast(fp16x2, b), c, false);
#else
  return fmaf((float)a[0], (float)b[0], fmaf((float)a[1], (float)b[1], c));
#endif
}
__device__ __forceinline__ float max8(const float* s) {
  float m = s[0];
  #pragma unroll
  for (int k = 1; k < 8; ++k) m = fmaxf(m, s[k]);
  return m;
}

__device__ __forceinline__ void leaf_ii(float xv, const float* mu8, const float* A8,
                                        const float* B8, half2v* ii, float* M) {
  float h[8];
  float m = -3.0e38f;
  #pragma unroll
  for (int k = 0; k < 8; ++k) {
    const float z = (xv - mu8[k]) * A8[k];
    h[k] = fmaf(-0.5f * z, z, B8[k]);
    m = fmaxf(m, h[k]);
  }
  #pragma unroll
  for (int k = 0; k < 8; ++k) {
    const float n = __expf(h[k] - m);
    ii[k] = pkrtz(n, n);
  }
  *M = m;
}
__device__ __forceinline__ void leaf_pk(float xv, const float* mu8, const float* A8,
                                        const float* B8, half2v* pk, float* M) {
  float h[8];
  float m = -3.0e38f;
  #pragma unroll
  for (int k = 0; k < 8; ++k) {
    const float z = (xv - mu8[k]) * A8[k];
    h[k] = fmaf(-0.5f * z, z, B8[k]);
    m = fmaxf(m, h[k]);
  }
  #pragma unroll
  for (int p = 0; p < 4; ++p) {
    const float n0 = __expf(h[2 * p] - m);
    const float n1 = __expf(h[2 * p + 1] - m);
    pk[p] = pkrtz(n0, n1);
  }
  *M = m;
}

// combine via dot2: s[k] = sum_{i,j} na_i nb_j W[i*8+j][k]
template<int G, bool OUT_II>
__device__ __forceinline__ void combine_d2(const uint4* __restrict__ WL,
                                           const half2v (&na)[G][8],
                                           const half2v (&nb)[G][4],
                                           half2v (&oii)[G][8],
                                           half2v (&opk)[G][4],
                                           float (&M)[G]) {
  float s[G][8];
  #pragma unroll
  for (int g = 0; g < G; ++g)
    #pragma unroll
    for (int k = 0; k < 8; ++k) s[g][k] = 0.f;

  #pragma unroll
  for (int i = 0; i < 8; ++i) {
    half2v e[G][4];
    #pragma unroll
    for (int g = 0; g < G; ++g) {
      e[g][0] = na[g][i] * nb[g][0];
      e[g][1] = na[g][i] * nb[g][1];
      e[g][2] = na[g][i] * nb[g][2];
      e[g][3] = na[g][i] * nb[g][3];
    }
    #pragma unroll
    for (int k = 0; k < 8; ++k) {
      const uint4 w = WL[i * 8 + k];
      #pragma unroll
      for (int g = 0; g < G; ++g) {
        float acc = s[g][k];
        acc = dd(e[g][0], u2h(w.x), acc);
        acc = dd(e[g][1], u2h(w.y), acc);
        acc = dd(e[g][2], u2h(w.z), acc);
        acc = dd(e[g][3], u2h(w.w), acc);
        s[g][k] = acc;
      }
    }
  }
  #pragma unroll
  for (int g = 0; g < G; ++g) {
    const float smax = max8(s[g]);
    const float inv = 1.0f / smax;
    if constexpr (OUT_II) {
      #pragma unroll
      for (int p = 0; p < 8; ++p) {
        const float n = s[g][p] * inv;
        oii[g][p] = pkrtz(n, n);
      }
    } else {
      #pragma unroll
      for (int p = 0; p < 4; ++p)
        opk[g][p] = pkrtz(s[g][2 * p] * inv, s[g][2 * p + 1] * inv);
    }
    M[g] += __logf(smax);
  }
}

// block-local softmax of one column (r,k) from stage into packed [c][k]-pair layout
__device__ __forceinline__ void prep_col_std(const float* stage, unsigned* wdwL,
                                             int r, int k) {
  float v[64];
  float m = -3.0e38f;
  #pragma unroll
  for (int c = 0; c < 64; ++c) { v[c] = stage[r * 512 + c * 8 + k]; m = fmaxf(m, v[c]); }
  float t = 0.f;
  #pragma unroll
  for (int c = 0; c < 64; ++c) { v[c] = __expf(v[c] - m); t += v[c]; }
  const float inv = 1.0f / t;
  #pragma unroll
  for (int i = 0; i < 8; ++i)
    #pragma unroll
    for (int jp = 0; jp < 4; ++jp)
      wdwL[r * 256 + (i * 8 + k) * 4 + jp] =
          h2u(pkrtz(v[i * 8 + 2 * jp] * inv, v[i * 8 + 2 * jp + 1] * inv));
}

// packed uint4 -> duplicated-pair form
__device__ __forceinline__ void mk_ii(uint4 p, half2v* ii) {
  const half2v a0 = u2h(p.x), a1 = u2h(p.y), a2 = u2h(p.z), a3 = u2h(p.w);
  ii[0] = __builtin_shufflevector(a0, a0, 0, 0);
  ii[1] = __builtin_shufflevector(a0, a0, 1, 1);
  ii[2] = __builtin_shufflevector(a1, a1, 0, 0);
  ii[3] = __builtin_shufflevector(a1, a1, 1, 1);
  ii[4] = __builtin_shufflevector(a2, a2, 0, 0);
  ii[5] = __builtin_shufflevector(a2, a2, 1, 1);
  ii[6] = __builtin_shufflevector(a3, a3, 0, 0);
  ii[7] = __builtin_shufflevector(a3, a3, 1, 1);
}

// 4-feature subtree (2x L0 + 1x L1) for G=2 batches, explicit weight/leaf pointers
template<bool OUT_II>
__device__ __forceinline__ void subtree_g2(
    const uint4* __restrict__ wA, const uint4* __restrict__ wB,
    const uint4* __restrict__ wT,
    const float* m0, const float* A0, const float* B0,
    float4 xa, float4 xb,
    half2v (&oii)[2][8], half2v (&opk)[2][4], float (&Mout)[2]) {
  half2v ii[2][8], pk[2][4];
  half2v aii[2][8], bpk[2][4];
  half2v dii[2][8], dpk[2][4];
  float Ma, Mb;

  leaf_ii(xa.x, m0,      A0,      B0,      ii[0], &Ma);
  leaf_pk(xa.y, m0 + 8,  A0 + 8,  B0 + 8,  pk[0], &Mb);
  float MA[2];
  MA[0] = Ma + Mb;
  leaf_ii(xb.x, m0,      A0,      B0,      ii[1], &Ma);
  leaf_pk(xb.y, m0 + 8,  A0 + 8,  B0 + 8,  pk[1], &Mb);
  MA[1] = Ma + Mb;
  combine_d2<2, true>(wA, ii, pk, aii, dpk, MA);

  leaf_ii(xa.z, m0 + 16, A0 + 16, B0 + 16, ii[0], &Ma);
  leaf_pk(xa.w, m0 + 24, A0 + 24, B0 + 24, pk[0], &Mb);
  float MB[2];
  MB[0] = Ma + Mb;
  leaf_ii(xb.z, m0 + 16, A0 + 16, B0 + 16, ii[1], &Ma);
  leaf_pk(xb.w, m0 + 24, A0 + 24, B0 + 24, pk[1], &Mb);
  MB[1] = Ma + Mb;
  combine_d2<2, false>(wB, ii, pk, dii, bpk, MB);

  float M[2] = {MA[0] + MB[0], MA[1] + MB[1]};
  combine_d2<2, OUT_II>(wT, aii, bpk, oii, opk, M);
  Mout[0] = M[0];
  Mout[1] = M[1];
}

// ===================== K1: fused L0..L3, in-block half-split, G=2 =====================
// grid: 16 r3 x 32 chunks = 512 blocks x 256 thr.
// phase 1: thread = (half h, u): half-subtree h (7 combines) for batches {u, u+128}.
// exchange L2 via LDS. phase 2: threads 0..127: L3 (G=2) -> ws.
// weight slots: L0 r(0..7)->0..7 | L1 -> 8..11 | L2 -> 12..13 | L3 -> 14
__global__ __launch_bounds__(NTH, 2) void spn_f(
    const float* __restrict__ x,
    const float* __restrict__ mu,
    const float* __restrict__ ls,
    const float* __restrict__ w0, const float* __restrict__ w1,
    const float* __restrict__ w2, const float* __restrict__ w3,
    float* __restrict__ ws)
{
  __shared__ float stage[7680];   // 30 KB; reused as exchange buffer after prep
  __shared__ uint4 wsh4[960];     // 15 regions x 64 uint4 = 15 KB packed f16
  __shared__ float lsh[384];      // mu/A/B for 16 features x 8
  const int tid = threadIdx.x;
  const int r3 = blockIdx.x >> 5;
  const int chunk = blockIdx.x & 31;

  #pragma unroll
  for (int i = 0; i < 30; ++i) {
    const int idx = tid + 256 * i;
    const int reg = idx >> 9, off = idx & 511;
    const float* src;
    if (reg < 8)       src = w0 + (8 * r3 + reg) * 512;
    else if (reg < 12) src = w1 + (4 * r3 + (reg - 8)) * 512;
    else if (reg < 14) src = w2 + (2 * r3 + (reg - 12)) * 512;
    else               src = w3 + r3 * 512;
    stage[idx] = src[off];
  }
  if (tid < 128) {
    const int base = r3 * 128;   // 16 features x 8
    const float l = ls[base + tid];
    lsh[tid]       = mu[base + tid];
    lsh[128 + tid] = __expf(-l);
    lsh[256 + tid] = -l - HLP;
  }
  __syncthreads();

  if (tid < 120) prep_col_std(stage, reinterpret_cast<unsigned*>(wsh4), tid >> 3, tid & 7);
  __syncthreads();   // stage is dead from here -> exchange buffer

  uint4* exN = reinterpret_cast<uint4*>(stage);   // [2 halves][256 lb] uint4 (8 KB)
  float* exM = stage + 2048;                      // [2 halves][256 lb] f32  (2 KB)

  // ---- phase 1: half-subtree (L0,L0,L1)x2 + L2 for G=2 batches ----
  const int h = tid >> 7;
  const int u = tid & 127;
  const int b0 = chunk * 256 + u;          // batches b0, b0+128
  {
    const float* xa = x + (size_t)b0 * 256 + 16 * r3 + 8 * h;
    const float* xb = x + (size_t)(b0 + 128) * 256 + 16 * r3 + 8 * h;
    const float4 xa0 = *reinterpret_cast<const float4*>(xa);
    const float4 xa1 = *reinterpret_cast<const float4*>(xa + 4);
    const float4 xb0 = *reinterpret_cast<const float4*>(xb);
    const float4 xb1 = *reinterpret_cast<const float4*>(xb + 4);

    const float* m0 = lsh + h * 64;
    const float* A0 = lsh + 128 + h * 64;
    const float* B0 = lsh + 256 + h * 64;
    const uint4* wL0 = wsh4 + (4 * h) * 64;
    const uint4* wL1 = wsh4 + (8 + 2 * h) * 64;
    const uint4* wL2 = wsh4 + (12 + h) * 64;

    half2v q0ii[2][8], q1pk[2][4];
    half2v dii[2][8], dpk[2][4];
    float Mq0[2], Mq1[2];

    subtree_g2<true >(wL0,        wL0 + 64,  wL1,      m0,      A0,      B0,
                      xa0, xb0, q0ii, dpk, Mq0);
    subtree_g2<false>(wL0 + 128,  wL0 + 192, wL1 + 64, m0 + 32, A0 + 32, B0 + 32,
                      xa1, xb1, dii, q1pk, Mq1);

    float M[2] = {Mq0[0] + Mq1[0], Mq0[1] + Mq1[1]};
    half2v n[2][4];
    combine_d2<2, false>(wL2, q0ii, q1pk, dii, n, M);

    exN[h * 256 + u]       = uint4{h2u(n[0][0]), h2u(n[0][1]), h2u(n[0][2]), h2u(n[0][3])};
    exN[h * 256 + u + 128] = uint4{h2u(n[1][0]), h2u(n[1][1]), h2u(n[1][2]), h2u(n[1][3])};
    exM[h * 256 + u]       = M[0];
    exM[h * 256 + u + 128] = M[1];
  }
  __syncthreads();

  // ---- phase 2: L3 (G=2) for batches {tid, tid+128}, threads 0..127 ----
  if (tid < 128) {
    const uint4 p0a = exN[tid], p0b = exN[tid + 128];              // half 0
    const uint4 p1a = exN[256 + tid], p1b = exN[256 + tid + 128];  // half 1
    float M[2];
    M[0] = exM[tid]       + exM[256 + tid];
    M[1] = exM[tid + 128] + exM[256 + tid + 128];

    half2v ii[2][8], pk[2][4];
    half2v dii[2][8];
    mk_ii(p0a, ii[0]);
    mk_ii(p0b, ii[1]);
    pk[0][0] = u2h(p1a.x); pk[0][1] = u2h(p1a.y); pk[0][2] = u2h(p1a.z); pk[0][3] = u2h(p1a.w);
    pk[1][0] = u2h(p1b.x); pk[1][1] = u2h(p1b.y); pk[1][2] = u2h(p1b.z); pk[1][3] = u2h(p1b.w);

    half2v n[2][4];
    combine_d2<2, false>(wsh4 + 14 * 64, ii, pk, dii, n, M);

    const int b = chunk * 256 + tid;
    uint4* outn = reinterpret_cast<uint4*>(ws);
    outn[r3 * 8192 + b]       = uint4{h2u(n[0][0]), h2u(n[0][1]), h2u(n[0][2]), h2u(n[0][3])};
    outn[r3 * 8192 + b + 128] = uint4{h2u(n[1][0]), h2u(n[1][1]), h2u(n[1][2]), h2u(n[1][3])};
    ws[L3MF + r3 * 8192 + b]       = M[0];
    ws[L3MF + r3 * 8192 + b + 128] = M[1];
  }
}

// ===================== K2: self-prep + layers 4..7 + root, k-parallel =====================
__device__ __forceinline__ float macTd(const uint4* __restrict__ Wr, int myk,
                                       const float* na, const half2v* nbpk) {
  float s = 0.f;
  #pragma unroll
  for (int i = 0; i < 8; ++i) {
    const uint4 w = Wr[myk * 8 + ((i ^ myk) & 7)];
    float T = dd(nbpk[0], u2h(w.x), 0.f);
    T = dd(nbpk[1], u2h(w.y), T);
    T = dd(nbpk[2], u2h(w.z), T);
    T = dd(nbpk[3], u2h(w.w), T);
    s = fmaf(na[i], T, s);
  }
  return s;
}

__global__ __launch_bounds__(NTH) void spn_c(
    const float* __restrict__ w4, const float* __restrict__ w5,
    const float* __restrict__ w6, const float* __restrict__ w7,
    const float* __restrict__ root_w,
    float* __restrict__ ws,
    float* __restrict__ out)
{
  __shared__ float stage[7680];   // 15 regions x 512 f32 = 30 KB
  __shared__ uint4 wsh4[960];     // 15 regions x 64 uint4 = 15 KB (transposed+swizzled)
  __shared__ float ssh[8];
  const int tid = threadIdx.x;

  #pragma unroll
  for (int i = 0; i < 30; ++i) {
    const int idx = tid + 256 * i;
    const int reg = idx >> 9, off = idx & 511;
    const float* src;
    if (reg < 8)       src = w4 + reg * 512;
    else if (reg < 12) src = w5 + (reg - 8) * 512;
    else if (reg < 14) src = w6 + (reg - 12) * 512;
    else               src = w7;
    stage[idx] = src[off];
  }
  if (tid == 255) {
    float m = -3.0e38f;
    for (int k = 0; k < 8; ++k) m = fmaxf(m, root_w[k]);
    float e[8]; float t = 0.f;
    for (int k = 0; k < 8; ++k) { e[k] = __expf(root_w[k] - m); t += e[k]; }
    const float inv = 1.0f / t;
    for (int k = 0; k < 8; ++k) ssh[k] = e[k] * inv;
  }
  __syncthreads();

  if (tid < 120) {
    // transposed [k][i][jp] packed with XOR-swizzled i-chunks
    const int reg = tid >> 3, k = tid & 7;
    float v[64];
    float m = -3.0e38f;
    #pragma unroll
    for (int c = 0; c < 64; ++c) { v[c] = stage[reg * 512 + c * 8 + k]; m = fmaxf(m, v[c]); }
    float t = 0.f;
    #pragma unroll
    for (int c = 0; c < 64; ++c) { v[c] = __expf(v[c] - m); t += v[c]; }
    const float inv = 1.0f / t;
    unsigned* wdwL = reinterpret_cast<unsigned*>(wsh4);
    #pragma unroll
    for (int i = 0; i < 8; ++i)
      #pragma unroll
      for (int jp = 0; jp < 4; ++jp)
        wdwL[reg * 256 + k * 32 + (((i ^ k) & 7) << 2) + jp] =
            h2u(pkrtz(v[i * 8 + 2 * jp] * inv, v[i * 8 + 2 * jp + 1] * inv));
  }
  __syncthreads();

  const int lane = tid & 63, wid = tid >> 6;
  const int myk = lane & 7, bsub = lane >> 3, gbase = lane & 56;
  const int b = blockIdx.x * 32 + wid * 8 + bsub;

  const uint4* n4 = reinterpret_cast<const uint4*>(ws);

  // ---- layer 4: 8 regions
  float n4v[8], M4[8];
  #pragma unroll
  for (int r = 0; r < 8; ++r) {
    const uint4 pa = n4[(2 * r + 0) * 8192 + b];
    const uint4 pb = n4[(2 * r + 1) * 8192 + b];
    const float Ma = ws[L3MF + (2 * r + 0) * 8192 + b];
    const float Mb = ws[L3MF + (2 * r + 1) * 8192 + b];
    float na[8];
    const half2v a0 = u2h(pa.x), a1 = u2h(pa.y), a2 = u2h(pa.z), a3 = u2h(pa.w);
    na[0] = (float)a0[0]; na[1] = (float)a0[1];
    na[2] = (float)a1[0]; na[3] = (float)a1[1];
    na[4] = (float)a2[0]; na[5] = (float)a2[1];
    na[6] = (float)a3[0]; na[7] = (float)a3[1];
    half2v nbpk[4] = {u2h(pb.x), u2h(pb.y), u2h(pb.z), u2h(pb.w)};
    float s = macTd(wsh4 + r * 64, myk, na, nbpk);
    float m = s;
    m = fmaxf(m, __shfl_xor(m, 1)); m = fmaxf(m, __shfl_xor(m, 2)); m = fmaxf(m, __shfl_xor(m, 4));
    n4v[r] = s / m;
    M4[r] = Ma + Mb + __logf(m);
  }

  // ---- layer 5: 4 regions
  float n5v[4], M5[4];
  #pragma unroll
  for (int r = 0; r < 4; ++r) {
    float na[8]; half2v nbpk[4];
    #pragma unroll
    for (int i = 0; i < 8; ++i) na[i] = __shfl(n4v[2 * r], gbase + i, 64);
    #pragma unroll
    for (int p = 0; p < 4; ++p)
      nbpk[p] = pkrtz(__shfl(n4v[2 * r + 1], gbase + 2 * p, 64),
                      __shfl(n4v[2 * r + 1], gbase + 2 * p + 1, 64));
    float s = macTd(wsh4 + (8 + r) * 64, myk, na, nbpk);
    float m = s;
    m = fmaxf(m, __shfl_xor(m, 1)); m = fmaxf(m, __shfl_xor(m, 2)); m = fmaxf(m, __shfl_xor(m, 4));
    n5v[r] = s / m;
    M5[r] = M4[2 * r] + M4[2 * r + 1] + __logf(m);
  }

  // ---- layer 6: 2 regions
  float n6v[2], M6[2];
  #pragma unroll
  for (int r = 0; r < 2; ++r) {
    float na[8]; half2v nbpk[4];
    #pragma unroll
    for (int i = 0; i < 8; ++i) na[i] = __shfl(n5v[2 * r], gbase + i, 64);
    #pragma unroll
    for (int p = 0; p < 4; ++p)
      nbpk[p] = pkrtz(__shfl(n5v[2 * r + 1], gbase + 2 * p, 64),
                      __shfl(n5v[2 * r + 1], gbase + 2 * p + 1, 64));
    float s = macTd(wsh4 + (12 + r) * 64, myk, na, nbpk);
    float m = s;
    m = fmaxf(m, __shfl_xor(m, 1)); m = fmaxf(m, __shfl_xor(m, 2)); m = fmaxf(m, __shfl_xor(m, 4));
    n6v[r] = s / m;
    M6[r] = M5[2 * r] + M5[2 * r + 1] + __logf(m);
  }

  // ---- layer 7 + root
  {
    float na[8]; half2v nbpk[4];
    #pragma unroll
    for (int i = 0; i < 8; ++i) na[i] = __shfl(n6v[0], gbase + i, 64);
    #pragma unroll
    for (int p = 0; p < 4; ++p)
      nbpk[p] = pkrtz(__shfl(n6v[1], gbase + 2 * p, 64),
                      __shfl(n6v[1], gbase + 2 * p + 1, 64));
    float s = macTd(wsh4 + 14 * 64, myk, na, nbpk);
    float m = s;
    m = fmaxf(m, __shfl_xor(m, 1)); m = fmaxf(m, __shfl_xor(m, 2)); m = fmaxf(m, __shfl_xor(m, 4));
    const float n7 = s / m;
    const float M7 = M6[0] + M6[1] + __logf(m);
    float prod = n7 * ssh[myk];
    prod += __shfl_xor(prod, 1); prod += __shfl_xor(prod, 2); prod += __shfl_xor(prod, 4);
    if (myk == 0) out[b] = M7 + __logf(prod);
  }
}

// ===================== fallback path (R1 kernel, proven 145us) =====================
static constexpr int NW   = 130560;
static constexpr int AOFF = NW;
static constexpr int BOFF = NW + 2048;
static constexpr int ROFF = NW + 4096;

__device__ __forceinline__ void leaf_eval(float xv, const float* mu8, const float* A8,
                                          const float* B8, float* n, float* M) {
  float h[8];
  float m = -3.0e38f;
  #pragma unroll
  for (int k = 0; k < 8; ++k) {
    const float z = (xv - mu8[k]) * A8[k];
    h[k] = fmaf(-0.5f * z, z, B8[k]);
    m = fmaxf(m, h[k]);
  }
  #pragma unroll
  for (int k = 0; k < 8; ++k) n[k] = __expf(h[k] - m);
  *M = m;
}

__global__ __launch_bounds__(256) void spn_prep(
    const float* __restrict__ ls,
    const float* __restrict__ w0, const float* __restrict__ w1,
    const float* __restrict__ w2, const float* __restrict__ w3,
    const float* __restrict__ w4, const float* __restrict__ w5,
    const float* __restrict__ w6, const float* __restrict__ w7,
    const float* __restrict__ root_w,
    float* __restrict__ ws)
{
  const int job = blockIdx.x * blockDim.x + threadIdx.x;
  if (job < 2040) {
    const float* wl[8] = {w0, w1, w2, w3, w4, w5, w6, w7};
    int j = job, l = 0, base = 0, R = 128;
    while (j >= R * 8) { j -= R * 8; base += R * 512; R >>= 1; ++l; }
    const int r = j >> 3, k = j & 7;
    const float* src = wl[l] + r * 512 + k;
    float v[64];
    float m = -3.0e38f;
    #pragma unroll
    for (int c = 0; c < 64; ++c) { v[c] = src[c * 8]; m = fmaxf(m, v[c]); }
    float ssum = 0.f;
    #pragma unroll
    for (int c = 0; c < 64; ++c) { v[c] = __expf(v[c] - m); ssum += v[c]; }
    const float inv = 1.0f / ssum;
    float* dst = ws + base + r * 512 + k;
    #pragma unroll
    for (int c = 0; c < 64; ++c) dst[c * 8] = v[c] * inv;
  } else if (job < 2040 + 2048) {
    const int i = job - 2040;
    const float l = ls[i];
    ws[AOFF + i] = __expf(-l);
    ws[BOFF + i] = -l - HLP;
  } else if (job == 2040 + 2048) {
    float m = -3.0e38f;
    for (int k = 0; k < 8; ++k) m = fmaxf(m, root_w[k]);
    float e[8]; float ssum = 0.f;
    for (int k = 0; k < 8; ++k) { e[k] = __expf(root_w[k] - m); ssum += e[k]; }
    const float inv = 1.0f / ssum;
    for (int k = 0; k < 8; ++k) ws[ROFF + k] = e[k] * inv;
  }
}

__device__ __forceinline__ void mac64(const float* __restrict__ Wr,
                                      const float* na, const float* nb,
                                      float* s) {
  #pragma unroll
  for (int k = 0; k < 8; ++k) s[k] = 0.f;
  #pragma unroll
  for (int i = 0; i < 8; ++i) {
    const float ai = na[i];
    #pragma unroll
    for (int j = 0; j < 8; ++j) {
      const float e = ai * nb[j];
      const float4 wA = *reinterpret_cast<const float4*>(Wr + (i * 8 + j) * 8);
      const float4 wB = *reinterpret_cast<const float4*>(Wr + (i * 8 + j) * 8 + 4);
      s[0] = fmaf(e, wA.x, s[0]); s[1] = fmaf(e, wA.y, s[1]);
      s[2] = fmaf(e, wA.z, s[2]); s[3] = fmaf(e, wA.w, s[3]);
      s[4] = fmaf(e, wB.x, s[4]); s[5] = fmaf(e, wB.y, s[5]);
      s[6] = fmaf(e, wB.z, s[6]); s[7] = fmaf(e, wB.w, s[7]);
    }
  }
}

#define TB 8
static constexpr int PLA = 128 * 9 + 5;
static constexpr int PLB = 64 * 9 + 5;
static constexpr int NAO = 0;
static constexpr int NBO = TB * PLA;
static constexpr int MAO = NBO + TB * PLB;
static constexpr int MBO = MAO + TB * 128;
static constexpr int SMEM_F = MBO + TB * 64;

__global__ __launch_bounds__(NTH, 2) void spn_main_fb(
    const float* __restrict__ x,
    const float* __restrict__ mu,
    const float* __restrict__ ws,
    float* __restrict__ out)
{
  const float* leafA = ws + AOFF;
  const float* leafB = ws + BOFF;
  const float* srw   = ws + ROFF;

  __shared__ float smem[SMEM_F];

  const int tid = threadIdx.x;
  const int bB = blockIdx.x * TB;

  {
    const float* W0 = ws;
    for (int it = tid; it < TB * 128; it += NTH) {
      const int bb = it & (TB - 1), r = it >> 3;
      float na[8], nb[8], Ma, Mb;
      const int f0 = 2 * r;
      const float xv0 = x[(bB + bb) * 256 + f0];
      const float xv1 = x[(bB + bb) * 256 + f0 + 1];
      leaf_eval(xv0, mu + f0 * 8, leafA + f0 * 8, leafB + f0 * 8, na, &Ma);
      leaf_eval(xv1, mu + f0 * 8 + 8, leafA + f0 * 8 + 8, leafB + f0 * 8 + 8, nb, &Mb);
      float s[8];
      mac64(W0 + r * 512, na, nb, s);
      const float smax = max8(s);
      const float inv = 1.0f / smax;
      const int ob = NAO + bb * PLA + r * 9;
      #pragma unroll
      for (int k = 0; k < 8; ++k) smem[ob + k] = s[k] * inv;
      smem[MAO + bb * 128 + r] = Ma + Mb + __logf(smax);
    }
  }
  __syncthreads();

  int pinO = NAO, poutO = NBO;
  int MinO = MAO, MoutO = MBO;
  int PLIN = PLA, PLOUT = PLB;
  int Rin = 128;
  const float* Wl = ws + 128 * 512;
  for (int l = 1; l < 7; ++l) {
    const int Rout = Rin >> 1;
    for (int it = tid; it < TB * Rout; it += NTH) {
      const int bb = it & (TB - 1), r = it >> 3;
      float na[8], nb[8];
      const int ia = pinO + bb * PLIN + (2 * r) * 9;
      #pragma unroll
      for (int i = 0; i < 8; ++i) { na[i] = smem[ia + i]; nb[i] = smem[ia + 9 + i]; }
      float s[8];
      mac64(Wl + r * 512, na, nb, s);
      const float smax = max8(s);
      const float inv = 1.0f / smax;
      const int ob = poutO + bb * PLOUT + r * 9;
      #pragma unroll
      for (int k = 0; k < 8; ++k) smem[ob + k] = s[k] * inv;
      smem[MoutO + bb * Rout + r] =
          smem[MinO + bb * Rin + 2 * r] + smem[MinO + bb * Rin + 2 * r + 1] + __logf(smax);
    }
    __syncthreads();
    int t;
    t = pinO; pinO = poutO; poutO = t;
    t = MinO; MinO = MoutO; MoutO = t;
    t = PLIN; PLIN = PLOUT; PLOUT = t;
    Rin = Rout;
    Wl += Rout * 512;
  }

  for (int it = tid; it < TB; it += NTH) {
    const int bb = it;
    float na[8], nb[8];
    const int ia = pinO + bb * PLIN;
    #pragma unroll
    for (int i = 0; i < 8; ++i) { na[i] = smem[ia + i]; nb[i] = smem[ia + 9 + i]; }
    float s[8];
    mac64(Wl, na, nb, s);
    float acc = 0.f;
    #pragma unroll
    for (int k = 0; k < 8; ++k) acc = fmaf(s[k], srw[k], acc);
    out[bB + bb] = smem[MinO + bb * 2] + smem[MinO + bb * 2 + 1] + __logf(acc);
  }
}

extern "C" void kernel_launch(void* const* d_in, const int* in_sizes, int n_in,
                              void* d_out, int out_size, void* d_ws, size_t ws_size,
                              hipStream_t stream) {
  (void)in_sizes; (void)n_in; (void)out_size;
  const float* x      = (const float*)d_in[0];
  const float* mu     = (const float*)d_in[1];
  const float* ls     = (const float*)d_in[2];
  const float* w0     = (const float*)d_in[3];
  const float* w1     = (const float*)d_in[4];
  const float* w2     = (const float*)d_in[5];
  const float* w3     = (const float*)d_in[6];
  const float* w4     = (const float*)d_in[7];
  const float* w5     = (const float*)d_in[8];
  const float* w6     = (const float*)d_in[9];
  const float* w7     = (const float*)d_in[10];
  const float* root_w = (const float*)d_in[11];
  float* ws  = (float*)d_ws;
  float* out = (float*)d_out;

  if (ws_size >= WS_NEED_B) {
    spn_f<<<512, NTH, 0, stream>>>(x, mu, ls, w0, w1, w2, w3, ws);
    spn_c<<<256, NTH, 0, stream>>>(w4, w5, w6, w7, root_w, ws, out);
  } else {
    spn_prep<<<16, 256, 0, stream>>>(ls, w0, w1, w2, w3, w4, w5, w6, w7, root_w, ws);
    spn_main_fb<<<8192 / TB, NTH, 0, stream>>>(x, mu, ws, out);
  }
}